// Round 1
// baseline (53.863 us; speedup 1.0000x reference)
//
#include <hip/hip_runtime.h>
#include <math.h>

#define SZ 28

__constant__ int c_fy[10] = {4,4,4,14,14,14,24,24,24,12};
__constant__ int c_fx[10] = {4,14,24,4,14,24,4,14,24,12};

// ---------------------------------------------------------------------------
// Prep: collapse exp(i*phase) * ifft2(H)-circular-conv into a [784][20] real
// weight matrix.  H is separable: H = h1(fx)*h1(fy), h1(f)=exp(-i*4*pi*f^2),
// so g = ifft2(H) = outer(g1, g1) with g1 = ifft(h1) (28-point DFT, done in
// double for exactness).
// W_p[y][x] = e^{i phase[y][x]} * g1[(y0p-y)%28] * g1[(x0p-x)%28]
// Layout: w[j*20 + p] = Re(W_p[j]),  w[j*20 + 10 + p] = Im(W_p[j])
// ---------------------------------------------------------------------------
__global__ void prep_weights(const float* __restrict__ phase,
                             float* __restrict__ w) {
    __shared__ double g1r[SZ], g1i[SZ];
    const int t = threadIdx.x;
    if (t < SZ) {
        double sr = 0.0, si = 0.0;
        for (int k = 0; k < SZ; ++k) {
            int m = (k <= SZ / 2) ? k : SZ - k;           // |fftfreq| numerator
            // angle of H1[k] is -pi*m^2/196 ; ifft twiddle +2*pi*k*t/28
            double ang = -M_PI * (double)(m * m) / 196.0
                       + 2.0 * M_PI * (double)(k * t) / (double)SZ;
            sr += cos(ang);
            si += sin(ang);
        }
        g1r[t] = sr / (double)SZ;
        g1i[t] = si / (double)SZ;
    }
    __syncthreads();
    if (t < SZ * SZ) {
        const int y = t / SZ, x = t % SZ;
        float sp, cp;
        sincosf(phase[t], &sp, &cp);
        #pragma unroll
        for (int p = 0; p < 10; ++p) {
            const int dy = (c_fy[p] - y + SZ) % SZ;
            const int dx = (c_fx[p] - x + SZ) % SZ;
            const float Gr = (float)(g1r[dy] * g1r[dx] - g1i[dy] * g1i[dx]);
            const float Gi = (float)(g1r[dy] * g1i[dx] + g1i[dy] * g1r[dx]);
            w[t * 20 + p]      = cp * Gr - sp * Gi;
            w[t * 20 + 10 + p] = cp * Gi + sp * Gr;
        }
    }
}

// ---------------------------------------------------------------------------
// Main: out[b,p] = (sum_j x[b,j]*Wr[j,p])^2 + (sum_j x[b,j]*Wi[j,p])^2
// Block = 256 threads = 4 waves; wave q owns j in [196q, 196q+196);
// lane owns batch row blockIdx.x*64+lane.  j is wave-uniform (readfirstlane)
// so w[] loads scalarize to s_load through the constant cache.
// Rows are 64B aligned (784 floats = 49 cache lines) -> every fetched line
// fully consumed.
// ---------------------------------------------------------------------------
__global__ __launch_bounds__(256) void focus_gemm(const float* __restrict__ x,
                                                  const float* __restrict__ w,
                                                  float* __restrict__ out) {
    const int lane = threadIdx.x & 63;
    const int q = __builtin_amdgcn_readfirstlane(threadIdx.x >> 6); // 0..3
    const int row = blockIdx.x * 64 + lane;

    float acc[20];
    #pragma unroll
    for (int k = 0; k < 20; ++k) acc[k] = 0.f;

    const float4* __restrict__ x4 = (const float4*)x;
    const int xbase = row * 196 + q * 49;              // row stride = 196 f4
    const float* __restrict__ wq = w + q * 196 * 20;

    for (int c = 0; c < 49; ++c) {
        const float4 xv = x4[xbase + c];
        const float* wj = wq + c * 80;                 // 4 j's * 20 coeffs
        #pragma unroll
        for (int jj = 0; jj < 4; ++jj) {
            const float xs = (&xv.x)[jj];
            #pragma unroll
            for (int k = 0; k < 20; ++k)
                acc[k] = fmaf(xs, wj[jj * 20 + k], acc[k]);
        }
    }

    __shared__ float red[4][64][20];                   // 20 KB
    #pragma unroll
    for (int k = 0; k < 20; ++k) red[q][lane][k] = acc[k];
    __syncthreads();

    if (threadIdx.x < 64) {
        float s[20];
        #pragma unroll
        for (int k = 0; k < 20; ++k)
            s[k] = red[0][threadIdx.x][k] + red[1][threadIdx.x][k]
                 + red[2][threadIdx.x][k] + red[3][threadIdx.x][k];
        const int r = blockIdx.x * 64 + threadIdx.x;
        #pragma unroll
        for (int p = 0; p < 10; ++p)
            out[r * 10 + p] = s[p] * s[p] + s[p + 10] * s[p + 10];
    }
}

extern "C" void kernel_launch(void* const* d_in, const int* in_sizes, int n_in,
                              void* d_out, int out_size, void* d_ws, size_t ws_size,
                              hipStream_t stream) {
    const float* x     = (const float*)d_in[0];   // [32768,1,28,28] f32
    const float* phase = (const float*)d_in[1];   // [28,28] f32
    float* out = (float*)d_out;                   // [32768,10] f32
    float* w   = (float*)d_ws;                    // 784*20 floats = 62720 B

    hipLaunchKernelGGL(prep_weights, dim3(1), dim3(SZ * SZ), 0, stream, phase, w);

    const int B = in_sizes[0] / (SZ * SZ);        // 32768
    hipLaunchKernelGGL(focus_gemm, dim3(B / 64), dim3(256), 0, stream, x, w, out);
}

// Round 2
// 41.495 us; speedup vs baseline: 1.2981x; 1.2981x over previous
//
#include <hip/hip_runtime.h>
#include <math.h>

#define SZ 28

__constant__ int c_fy[10] = {4,4,4,14,14,14,24,24,24,12};
__constant__ int c_fx[10] = {4,14,24,4,14,24,4,14,24,12};

// ---------------------------------------------------------------------------
// Prep: collapse exp(i*phase) * ifft2(H) circular conv into [784][20] weights.
// H separable: g = ifft2(H) = outer(g1,g1), g1 = ifft(h1), h1=exp(-i*4*pi*f^2).
// Parallel 28-pt DFT: thread (t,k) computes one twiddle term (double), 28-term
// LDS reduce. Then per-pixel: W_p = e^{i phase} * g1[(y0-y)%28] * g1[(x0-x)%28].
// Layout: w[j*20+p]=Re, w[j*20+10+p]=Im.
// ---------------------------------------------------------------------------
__global__ void prep_weights(const float* __restrict__ phase,
                             float* __restrict__ w) {
    __shared__ double tr[SZ][SZ], ti[SZ][SZ];       // [t][k]
    __shared__ float g1r[SZ], g1i[SZ];
    const int tid = threadIdx.x;                    // 0..783
    {
        const int t = tid / SZ, k = tid % SZ;
        const int m = (k <= SZ / 2) ? k : SZ - k;   // |fftfreq| numerator
        const double ang = -M_PI * (double)(m * m) / 196.0
                         + 2.0 * M_PI * (double)((k * t) % SZ) / (double)SZ;
        tr[t][k] = cos(ang);
        ti[t][k] = sin(ang);
    }
    __syncthreads();
    if (tid < SZ) {
        double ar = 0.0, ai = 0.0;
        for (int k = 0; k < SZ; ++k) { ar += tr[tid][k]; ai += ti[tid][k]; }
        g1r[tid] = (float)(ar / (double)SZ);
        g1i[tid] = (float)(ai / (double)SZ);
    }
    __syncthreads();
    {
        const int y = tid / SZ, x = tid % SZ;
        float sp, cp;
        sincosf(phase[tid], &sp, &cp);
        #pragma unroll
        for (int p = 0; p < 10; ++p) {
            const int dy = (c_fy[p] - y + SZ) % SZ;
            const int dx = (c_fx[p] - x + SZ) % SZ;
            const float Gr = g1r[dy] * g1r[dx] - g1i[dy] * g1i[dx];
            const float Gi = g1r[dy] * g1i[dx] + g1i[dy] * g1r[dx];
            w[tid * 20 + p]      = cp * Gr - sp * Gi;
            w[tid * 20 + 10 + p] = cp * Gi + sp * Gr;
        }
    }
}

// ---------------------------------------------------------------------------
// Main: out[b,p] = (sum_j x[b,j]*Wr[j,p])^2 + (sum_j x[b,j]*Wi[j,p])^2
// Block = 448 threads = 7 waves; wave q owns f4-columns [28q, 28q+28);
// lane owns batch row blockIdx.x*64+lane. j is wave-uniform -> w loads
// scalarize (s_load via constant cache). unroll 7 -> 7 float4 loads in
// flight per wave. LDS reduce padded to 21 (odd stride = conflict-free).
// ---------------------------------------------------------------------------
__global__ __launch_bounds__(448) void focus_gemm(const float* __restrict__ x,
                                                  const float* __restrict__ w,
                                                  float* __restrict__ out) {
    const int lane = threadIdx.x & 63;
    const int q = __builtin_amdgcn_readfirstlane((int)threadIdx.x >> 6); // 0..6
    const int row = blockIdx.x * 64 + lane;

    float acc[20];
    #pragma unroll
    for (int k = 0; k < 20; ++k) acc[k] = 0.f;

    const float4* __restrict__ x4 = (const float4*)x;
    const int xbase = row * 196 + q * 28;            // row stride = 196 f4
    const float* __restrict__ wq = w + q * 28 * 80;  // 80 floats per f4-col

    #pragma unroll 7
    for (int c = 0; c < 28; ++c) {
        const float4 xv = x4[xbase + c];
        const float* wj = wq + c * 80;
        #pragma unroll
        for (int jj = 0; jj < 4; ++jj) {
            const float xs = (&xv.x)[jj];
            #pragma unroll
            for (int k = 0; k < 20; ++k)
                acc[k] = fmaf(xs, wj[jj * 20 + k], acc[k]);
        }
    }

    __shared__ float red[7][64][21];                 // 36.75 KB, odd stride
    #pragma unroll
    for (int k = 0; k < 20; ++k) red[q][lane][k] = acc[k];
    __syncthreads();

    if (threadIdx.x < 64) {
        const int t = threadIdx.x;
        float s[20];
        #pragma unroll
        for (int k = 0; k < 20; ++k) {
            float v = red[0][t][k];
            #pragma unroll
            for (int p = 1; p < 7; ++p) v += red[p][t][k];
            s[k] = v;
        }
        const int r = blockIdx.x * 64 + t;
        float2* o2 = (float2*)(out + r * 10);
        #pragma unroll
        for (int p = 0; p < 5; ++p) {
            float2 v;
            v.x = s[2 * p]     * s[2 * p]     + s[2 * p + 10] * s[2 * p + 10];
            v.y = s[2 * p + 1] * s[2 * p + 1] + s[2 * p + 11] * s[2 * p + 11];
            o2[p] = v;
        }
    }
}

extern "C" void kernel_launch(void* const* d_in, const int* in_sizes, int n_in,
                              void* d_out, int out_size, void* d_ws, size_t ws_size,
                              hipStream_t stream) {
    const float* x     = (const float*)d_in[0];   // [32768,1,28,28] f32
    const float* phase = (const float*)d_in[1];   // [28,28] f32
    float* out = (float*)d_out;                   // [32768,10] f32
    float* w   = (float*)d_ws;                    // 784*20 floats

    hipLaunchKernelGGL(prep_weights, dim3(1), dim3(SZ * SZ), 0, stream, phase, w);

    const int B = in_sizes[0] / (SZ * SZ);        // 32768
    hipLaunchKernelGGL(focus_gemm, dim3(B / 64), dim3(448), 0, stream, x, w, out);
}

// Round 3
// 40.488 us; speedup vs baseline: 1.3303x; 1.0249x over previous
//
#include <hip/hip_runtime.h>
#include <math.h>

#define SZ 28

__constant__ int c_fy[10] = {4,4,4,14,14,14,24,24,24,12};
__constant__ int c_fx[10] = {4,14,24,4,14,24,4,14,24,12};

// ---------------------------------------------------------------------------
// Prep: collapse exp(i*phase) * ifft2(H) circular conv into [784][20] weights.
// H separable: g = ifft2(H) = outer(g1,g1), g1 = ifft(h1), h1=exp(-i*4*pi*f^2).
// ---------------------------------------------------------------------------
__global__ void prep_weights(const float* __restrict__ phase,
                             float* __restrict__ w) {
    __shared__ double tr[SZ][SZ], ti[SZ][SZ];       // [t][k]
    __shared__ float g1r[SZ], g1i[SZ];
    const int tid = threadIdx.x;                    // 0..783
    {
        const int t = tid / SZ, k = tid % SZ;
        const int m = (k <= SZ / 2) ? k : SZ - k;   // |fftfreq| numerator
        const double ang = -M_PI * (double)(m * m) / 196.0
                         + 2.0 * M_PI * (double)((k * t) % SZ) / (double)SZ;
        tr[t][k] = cos(ang);
        ti[t][k] = sin(ang);
    }
    __syncthreads();
    if (tid < SZ) {
        double ar = 0.0, ai = 0.0;
        for (int k = 0; k < SZ; ++k) { ar += tr[tid][k]; ai += ti[tid][k]; }
        g1r[tid] = (float)(ar / (double)SZ);
        g1i[tid] = (float)(ai / (double)SZ);
    }
    __syncthreads();
    {
        const int y = tid / SZ, x = tid % SZ;
        float sp, cp;
        sincosf(phase[tid], &sp, &cp);
        #pragma unroll
        for (int p = 0; p < 10; ++p) {
            const int dy = (c_fy[p] - y + SZ) % SZ;
            const int dx = (c_fx[p] - x + SZ) % SZ;
            const float Gr = g1r[dy] * g1r[dx] - g1i[dy] * g1i[dx];
            const float Gi = g1r[dy] * g1i[dx] + g1i[dy] * g1r[dx];
            w[tid * 20 + p]      = cp * Gr - sp * Gi;
            w[tid * 20 + 10 + p] = cp * Gi + sp * Gr;
        }
    }
}

// ---------------------------------------------------------------------------
// Main: out[b,p] = (sum_j x[b,j]*Wr[j,p])^2 + (sum_j x[b,j]*Wi[j,p])^2
// Block = 448 thr = 7 waves, owns 64 contiguous rows. K (196 f4-cols) is
// processed in 7 chunks of 28 f4-cols, double-buffered through LDS via
// global_load_lds (width 16). LDS tile is [row][32 f4] with col^(row&31)
// XOR swizzle applied on the SOURCE side (gll dest is linear) so that:
//   - global side: each instr covers 2 contiguous 448B row-slices (~15 lines)
//   - LDS read side: ds_read_b128 at [lane][j^lane] = 2 lanes/bank (free)
// w indices wave-uniform -> scalar loads. Reduction LDS unioned over buffers.
// ---------------------------------------------------------------------------
__device__ static inline void gload_lds16(const float* src, char* lds_dst) {
    __builtin_amdgcn_global_load_lds(
        (const __attribute__((address_space(1))) void*)src,
        (__attribute__((address_space(3))) void*)lds_dst, 16, 0, 0);
}

__global__ __launch_bounds__(448) void focus_gemm(const float* __restrict__ x,
                                                  const float* __restrict__ w,
                                                  float* __restrict__ out) {
    __shared__ char smem[65536];                 // 2 x 32KB buffers (union: red)

    const int tid  = threadIdx.x;
    const int lane = tid & 63;
    const int q = __builtin_amdgcn_readfirstlane(tid >> 6);   // wave 0..6
    const int row0 = blockIdx.x * 64;

    float acc[20];
    #pragma unroll
    for (int k = 0; k < 20; ++k) acc[k] = 0.f;

    // ---- stage chunk c into buffer b (slots s = i*64+lane, i wave-strided) ----
    // slot s -> row r = s>>5, jsw = s&31, col j = jsw ^ (r&31); j>=28 -> pad.
    auto stage = [&](int b, int c) {
        char* buf = smem + b * 32768;
        for (int i = q; i < 32; i += 7) {
            const int s   = i * 64 + lane;
            const int r   = s >> 5;
            const int j   = (s & 31) ^ (r & 31);
            const float* src = (j < 28)
                ? (x + (size_t)(row0 + r) * 784 + (size_t)(c * 28 + j) * 4)
                : x;                                   // pad slot: dummy line
            gload_lds16(src, buf + (size_t)i * 1024);  // dest wave-uniform
        }
    };

    stage(0, 0);                                   // prologue
    for (int c = 0; c < 7; ++c) {
        const int cur = c & 1;
        __syncthreads();                           // drains gll (vmcnt) + sync
        if (c + 1 < 7) stage(cur ^ 1, c + 1);      // next chunk flies under FMAs
        const float4* buf = (const float4*)(smem + cur * 32768);
        #pragma unroll
        for (int jj = 0; jj < 4; ++jj) {
            const int j = 4 * q + jj;              // f4-col within chunk, 0..27
            const float4 xv = buf[(size_t)lane * 32 + (j ^ (lane & 31))];
            const float* wj = w + (size_t)(c * 28 + j) * 80;
            #pragma unroll
            for (int e = 0; e < 4; ++e) {
                const float xs = (&xv.x)[e];
                #pragma unroll
                for (int k = 0; k < 20; ++k)
                    acc[k] = fmaf(xs, wj[e * 20 + k], acc[k]);
            }
        }
    }

    __syncthreads();                               // all reads of bufs done
    float* red = (float*)smem;                     // [7][64][21] = 37.6 KB
    #pragma unroll
    for (int k = 0; k < 20; ++k) red[(q * 64 + lane) * 21 + k] = acc[k];
    __syncthreads();

    if (tid < 64) {
        float s[20];
        #pragma unroll
        for (int k = 0; k < 20; ++k) {
            float v = red[tid * 21 + k];
            #pragma unroll
            for (int p = 1; p < 7; ++p) v += red[(p * 64 + tid) * 21 + k];
            s[k] = v;
        }
        float2* o2 = (float2*)(out + (size_t)(row0 + tid) * 10);
        #pragma unroll
        for (int p = 0; p < 5; ++p) {
            float2 v;
            v.x = s[2*p]   * s[2*p]   + s[2*p+10] * s[2*p+10];
            v.y = s[2*p+1] * s[2*p+1] + s[2*p+11] * s[2*p+11];
            o2[p] = v;
        }
    }
}

extern "C" void kernel_launch(void* const* d_in, const int* in_sizes, int n_in,
                              void* d_out, int out_size, void* d_ws, size_t ws_size,
                              hipStream_t stream) {
    const float* x     = (const float*)d_in[0];   // [32768,1,28,28] f32
    const float* phase = (const float*)d_in[1];   // [28,28] f32
    float* out = (float*)d_out;                   // [32768,10] f32
    float* w   = (float*)d_ws;                    // 784*20 floats

    hipLaunchKernelGGL(prep_weights, dim3(1), dim3(SZ * SZ), 0, stream, phase, w);

    const int B = in_sizes[0] / (SZ * SZ);        // 32768
    hipLaunchKernelGGL(focus_gemm, dim3(B / 64), dim3(448), 0, stream, x, w, out);
}